// Round 18
// baseline (369.734 us; speedup 1.0000x reference)
//
#include <hip/hip_runtime.h>

typedef unsigned int uint32;
typedef unsigned short ushort16;
typedef unsigned long long u64;
using short8 = __attribute__((ext_vector_type(8))) short;
using f32x4  = __attribute__((ext_vector_type(4))) float;

__device__ __forceinline__ float bfl(uint32 v) { return __uint_as_float(v << 16); }
__device__ __forceinline__ float bfh(uint32 v) { return __uint_as_float(v & 0xffff0000u); }
__device__ __forceinline__ ushort16 f2bf(float f) {
    uint32 u = __float_as_uint(f);
    u += 0x7fffu + ((u >> 16) & 1u);   // RNE
    return (ushort16)(u >> 16);
}
__device__ __forceinline__ uint32 pack2(float x, float y) {
    return (uint32)f2bf(x) | ((uint32)f2bf(y) << 16);
}

// ---------------- CSR build: LDS-binned two-phase partition ----------------
// Grid 1024 -> ~12 deposits per bin-block: mid-loop flush is dead weight.
// LCAP 24 (31.4 KB LDS -> 5 blocks/CU), barrier-free deposit, single final flush.

constexpr int BIN_SH   = 10;
constexpr int CAP_PAIR = 16384;
constexpr int LCAP     = 24;
constexpr int NBIN_MAX = 160;

struct CvtWArgs { const float* W[6]; ushort16* Wt[6]; };

__global__ void init_ccur_kernel(int* __restrict__ ccur, int nbin) {
    int b = threadIdx.x;
    if (b < nbin) ccur[b] = b * CAP_PAIR;
}

__global__ __launch_bounds__(256) void part_a_kernel(
        const int* __restrict__ s0, const int* __restrict__ d0,
        const int* __restrict__ s1, const int* __restrict__ d1,
        const int* __restrict__ s2, const int* __restrict__ d2,
        int e0, int e01, int e012, int o1, int o2, int nbin,
        int* __restrict__ ccur, u64* __restrict__ cpair, CvtWArgs a) {
    __shared__ u64 buf[NBIN_MAX][LCAP];
    __shared__ int lcnt[NBIN_MAX];
    const int tid = threadIdx.x;
    for (int b = tid; b < nbin; b += 256) lcnt[b] = 0;
    __syncthreads();
    const int step = gridDim.x * 1024;
    for (int base = blockIdx.x * 1024; base < e012; base += step) {
        #pragma unroll
        for (int k = 0; k < 4; ++k) {              // 4 independent coalesced loads
            int i = base + tid + k * 256;
            if (i < e012) {
                int g, sv;
                if (i < e0)       { g = d0[i];            sv = s0[i]; }
                else if (i < e01) { g = o1 + d1[i - e0];  sv = s1[i - e0]; }
                else              { g = o2 + d2[i - e01]; sv = s2[i - e01]; }
                int bin = g >> BIN_SH;
                u64 pr = ((u64)(uint32)g << 32) | (uint32)sv;
                int slot = atomicAdd(&lcnt[bin], 1);
                if (slot < LCAP) {
                    buf[bin][slot] = pr;
                } else {                           // rare overflow: direct append
                    int p = atomicAdd(&ccur[bin], 1);
                    cpair[p] = pr;
                    atomicSub(&lcnt[bin], 1);
                }
            }
        }
    }
    __syncthreads();
    if (tid < nbin) {                              // single final flush (~12 pairs)
        int cnt = min(lcnt[tid], LCAP);
        if (cnt > 0) {
            int p = atomicAdd(&ccur[tid], cnt);
            for (int k = 0; k < cnt; ++k) cpair[p + k] = buf[tid][k];
        }
    }
    // ---- cvtW tail (independent; W[k][M] fp32 -> Wt[n][k] bf16) ----
    const int gid = blockIdx.x * 256 + tid;
    const int gstep = gridDim.x * 256;
    for (int i = gid; i < 3 * 16384 + 3 * 8192; i += gstep) {
        if (i < 3 * 16384) {
            int m = i / 16384, idx = i % 16384;
            int n = idx >> 7, k = idx & 127;
            a.Wt[m][n * 128 + k] = f2bf(a.W[m][k * 128 + n]);
        } else {
            int j = i - 3 * 16384;
            int m = 3 + j / 8192, idx = j % 8192;
            int n = idx >> 7, k = idx & 127;
            a.Wt[m][n * 128 + k] = f2bf(a.W[m][k * 64 + n]);
        }
    }
}

// per-bin: inline bin-count scan -> LDS deg hist -> LDS scan -> rs -> scatter
__global__ __launch_bounds__(256) void part_b_kernel(const u64* __restrict__ cpair,
                                                     const int* __restrict__ ccur,
                                                     int nbin, int tn, int e012,
                                                     int* __restrict__ rs,
                                                     int* __restrict__ esrc) {
    __shared__ int cofs_l[NBIN_MAX + 1];
    __shared__ int rs_l[1024];
    __shared__ int cur_l[1024];
    __shared__ int tsum[256];
    const int bin = blockIdx.x;
    const int t = threadIdx.x;
    // wave 0: exclusive scan of bin counts (from final cursors)
    if (t < 64) {
        int lane = t;
        int run = 0;
        for (int base = 0; base < nbin; base += 64) {
            int b = base + lane;
            int c = (b < nbin) ? (ccur[b] - b * CAP_PAIR) : 0;
            int v = c;
            #pragma unroll
            for (int off = 1; off < 64; off <<= 1) {
                int u = __shfl_up(v, off);
                if (lane >= off) v += u;
            }
            if (b < nbin) cofs_l[b] = run + (v - c);
            run += __shfl(v, 63);
        }
        if (lane == 0) cofs_l[nbin] = run;
    }
    #pragma unroll
    for (int k = 0; k < 4; ++k) cur_l[t + k * 256] = 0;
    __syncthreads();
    const int g0 = bin << BIN_SH;
    const int gcnt = min(1024, tn - g0);
    const int pbase = bin * CAP_PAIR;
    const int obase = cofs_l[bin];
    const int cnt = cofs_l[bin + 1] - obase;
    for (int i = t; i < cnt; i += 256) {
        int g = (int)(cpair[pbase + i] >> 32);
        atomicAdd(&cur_l[g - g0], 1);
    }
    __syncthreads();
    int v[4]; int s = 0;
    #pragma unroll
    for (int k = 0; k < 4; ++k) { v[k] = cur_l[t * 4 + k]; s += v[k]; }
    tsum[t] = s;
    __syncthreads();
    for (int off = 1; off < 256; off <<= 1) {
        int add = (t >= off) ? tsum[t - off] : 0;
        __syncthreads();
        tsum[t] += add;
        __syncthreads();
    }
    int run = (t ? tsum[t - 1] : 0);
    #pragma unroll
    for (int k = 0; k < 4; ++k) { rs_l[t * 4 + k] = run; run += v[k]; }
    __syncthreads();
    #pragma unroll
    for (int k = 0; k < 4; ++k) {
        int j = t + k * 256;
        if (j < gcnt) rs[g0 + j] = obase + rs_l[j];
    }
    if (bin == nbin - 1 && t == 0) rs[tn] = e012;
    #pragma unroll
    for (int k = 0; k < 4; ++k) cur_l[t + k * 256] = 0;
    __syncthreads();
    for (int i = t; i < cnt; i += 256) {
        u64 pr = cpair[pbase + i];
        int g = (int)(pr >> 32);
        int p = atomicAdd(&cur_l[g - g0], 1);
        esrc[obase + rs_l[g - g0] + p] = (int)(uint32)(pr & 0xffffffffu);
    }
}

// ---------------- fused triple GEMM, LDS-staged 64-row tiles (round-14 form) ----------------

struct Gemm3Args {
    const void* A[3];
    const ushort16* Wt[3];
    ushort16* Y[3];
    int N[3];
    int nb0, nb01;
};

template<int M, bool F32A>
__global__ __launch_bounds__(256) void gemm3_kernel(Gemm3Args g) {
    constexpr int NTW = M / 64;
    constexpr int CH  = M / 8;
    __shared__ short8 As[64 * 16];
    int b = blockIdx.x;
    int r = (b < g.nb0) ? 0 : ((b < g.nb01) ? 1 : 2);
    int bloc = b - ((r == 0) ? 0 : ((r == 1) ? g.nb0 : g.nb01));
    const int N = g.N[r];
    const int row0 = bloc * 64;
    const int tid = threadIdx.x;
    const int w = tid >> 6, l = tid & 63;
    const int lr = l & 15, lg = l >> 4;

    #pragma unroll
    for (int it = 0; it < 4; ++it) {
        int idx = it * 256 + tid;
        int row = idx >> 4, c = idx & 15;
        int grow = row0 + row;
        short8 v = {0, 0, 0, 0, 0, 0, 0, 0};
        if (grow < N) {
            if (F32A) {
                const float* gp = (const float*)g.A[r] + (size_t)grow * 128 + c * 8;
                float4 f0 = *(const float4*)gp;
                float4 f1 = *(const float4*)(gp + 4);
                v[0] = (short)f2bf(f0.x); v[1] = (short)f2bf(f0.y);
                v[2] = (short)f2bf(f0.z); v[3] = (short)f2bf(f0.w);
                v[4] = (short)f2bf(f1.x); v[5] = (short)f2bf(f1.y);
                v[6] = (short)f2bf(f1.z); v[7] = (short)f2bf(f1.w);
            } else {
                v = *(const short8*)((const ushort16*)g.A[r] + (size_t)grow * 128 + c * 8);
            }
        }
        As[row * 16 + (c ^ (row & 7))] = v;
    }
    __syncthreads();

    short8 bf[NTW][4];
    #pragma unroll
    for (int t = 0; t < NTW; ++t) {
        int n = w * (NTW * 16) + t * 16 + lr;
        const ushort16* wr = g.Wt[r] + (size_t)n * 128 + lg * 8;
        #pragma unroll
        for (int ks = 0; ks < 4; ++ks) bf[t][ks] = *(const short8*)(wr + ks * 32);
    }

    f32x4 acc[4][NTW];
    #pragma unroll
    for (int rt = 0; rt < 4; ++rt)
        #pragma unroll
        for (int t = 0; t < NTW; ++t) acc[rt][t] = (f32x4){0.f, 0.f, 0.f, 0.f};

    #pragma unroll
    for (int rt = 0; rt < 4; ++rt) {
        int row = rt * 16 + lr;
        short8 a[4];
        #pragma unroll
        for (int ks = 0; ks < 4; ++ks)
            a[ks] = As[row * 16 + ((lg + ks * 4) ^ (lr & 7))];
        #pragma unroll
        for (int t = 0; t < NTW; ++t)
            #pragma unroll
            for (int ks = 0; ks < 4; ++ks)
                acc[rt][t] = __builtin_amdgcn_mfma_f32_16x16x32_bf16(a[ks], bf[t][ks],
                                                                     acc[rt][t], 0, 0, 0);
    }

    __syncthreads();
    ushort16* Ys = (ushort16*)As;
    #pragma unroll
    for (int rt = 0; rt < 4; ++rt) {
        int row = rt * 16 + lg * 4;
        #pragma unroll
        for (int t = 0; t < NTW; ++t) {
            int col = w * (NTW * 16) + t * 16 + lr;
            int chx = (col >> 3);
            #pragma unroll
            for (int j = 0; j < 4; ++j) {
                int rr = row + j;
                Ys[rr * M + ((chx ^ (rr & 7)) << 3) + (col & 7)] = f2bf(acc[rt][t][j]);
            }
        }
    }
    __syncthreads();
    ushort16* Y = g.Y[r];
    #pragma unroll
    for (int it = 0; it < 64 * CH / 256; ++it) {
        int idx = it * 256 + tid;
        int row = idx / CH, c = idx % CH;
        int grow = row0 + row;
        if (grow < N) {
            short8 v = *(const short8*)&Ys[row * M + ((c ^ (row & 7)) << 3)];
            *(short8*)(Y + (size_t)grow * M + c * 8) = v;
        }
    }
}

// ---------------- fused aggregation (round-14 form: agg1 unroll-2) ----------------

__global__ __launch_bounds__(256) void agg1_kernel(const uint4* __restrict__ tbA,
                                                   const uint4* __restrict__ tbB,
                                                   const uint4* __restrict__ tbC,
                                                   const int* __restrict__ esrc,
                                                   const int* __restrict__ rs,
                                                   const float* __restrict__ bA,
                                                   const float* __restrict__ bB,
                                                   const float* __restrict__ bC,
                                                   uint4* __restrict__ hd,
                                                   uint4* __restrict__ hp,
                                                   int ND, int NP, int o1, int o2) {
    __shared__ int sidx[4][64];
    const int w = threadIdx.x >> 6;
    const int lane = threadIdx.x & 63;
    const int wid = blockIdx.x * 4 + w;
    const int q = lane >> 4, c = lane & 15;
    if (wid >= ND + NP) return;
    float acc[8];
    auto zero = [&]() {
        for (int k = 0; k < 8; ++k) acc[k] = 0.f;
    };
    auto gather = [&](const uint4* __restrict__ tb, int e0, int e1) {
        for (int base = e0; base < e1; base += 64) {
            int cnt = min(64, e1 - base);
            if (lane < cnt) sidx[w][lane] = esrc[base + lane];
            int j = q;
            for (; j + 4 < cnt; j += 8) {
                uint4 v0 = tb[(size_t)sidx[w][j] * 16 + c];
                uint4 v1 = tb[(size_t)sidx[w][j + 4] * 16 + c];
                acc[0] += bfl(v0.x) + bfl(v1.x);  acc[1] += bfh(v0.x) + bfh(v1.x);
                acc[2] += bfl(v0.y) + bfl(v1.y);  acc[3] += bfh(v0.y) + bfh(v1.y);
                acc[4] += bfl(v0.z) + bfl(v1.z);  acc[5] += bfh(v0.z) + bfh(v1.z);
                acc[6] += bfl(v0.w) + bfl(v1.w);  acc[7] += bfh(v0.w) + bfh(v1.w);
            }
            if (j < cnt) {
                uint4 v0 = tb[(size_t)sidx[w][j] * 16 + c];
                acc[0] += bfl(v0.x);  acc[1] += bfh(v0.x);
                acc[2] += bfl(v0.y);  acc[3] += bfh(v0.y);
                acc[4] += bfl(v0.z);  acc[5] += bfh(v0.z);
                acc[6] += bfl(v0.w);  acc[7] += bfh(v0.w);
            }
        }
        #pragma unroll
        for (int k = 0; k < 8; ++k) {
            acc[k] += __shfl_xor(acc[k], 16);
            acc[k] += __shfl_xor(acc[k], 32);
        }
    };
    if (wid < ND) {
        int e0 = rs[wid], e1 = rs[wid + 1];
        zero();
        gather(tbA, e0, e1);
        if (lane < 16) {
            float inv = 1.f / (float)max(e1 - e0, 1);
            float4 b0 = ((const float4*)bA)[c * 2];
            float4 b1 = ((const float4*)bA)[c * 2 + 1];
            hd[(size_t)wid * 16 + c] = make_uint4(
                pack2(acc[0] * inv + b0.x, acc[1] * inv + b0.y),
                pack2(acc[2] * inv + b0.z, acc[3] * inv + b0.w),
                pack2(acc[4] * inv + b1.x, acc[5] * inv + b1.y),
                pack2(acc[6] * inv + b1.z, acc[7] * inv + b1.w));
        }
    } else {
        int p = wid - ND;
        int g1 = o1 + p, g2 = o2 + p;
        int e0 = rs[g1], e1 = rs[g1 + 1];
        zero();
        gather(tbB, e0, e1);
        float res[8];
        float inv1 = 1.f / (float)max(e1 - e0, 1);
        #pragma unroll
        for (int k = 0; k < 8; ++k) res[k] = acc[k] * inv1;
        int f0 = rs[g2], f1 = rs[g2 + 1];
        zero();
        gather(tbC, f0, f1);
        if (lane < 16) {
            float inv2 = 1.f / (float)max(f1 - f0, 1);
            float4 bb0 = ((const float4*)bB)[c * 2];
            float4 bb1 = ((const float4*)bB)[c * 2 + 1];
            float4 bc0 = ((const float4*)bC)[c * 2];
            float4 bc1 = ((const float4*)bC)[c * 2 + 1];
            float r0 = res[0] + acc[0] * inv2 + bb0.x + bc0.x;
            float r1 = res[1] + acc[1] * inv2 + bb0.y + bc0.y;
            float r2 = res[2] + acc[2] * inv2 + bb0.z + bc0.z;
            float r3 = res[3] + acc[3] * inv2 + bb0.w + bc0.w;
            float r4 = res[4] + acc[4] * inv2 + bb1.x + bc1.x;
            float r5 = res[5] + acc[5] * inv2 + bb1.y + bc1.y;
            float r6 = res[6] + acc[6] * inv2 + bb1.z + bc1.z;
            float r7 = res[7] + acc[7] * inv2 + bb1.w + bc1.w;
            hp[(size_t)p * 16 + c] = make_uint4(pack2(r0, r1), pack2(r2, r3),
                                                pack2(r4, r5), pack2(r6, r7));
        }
    }
}

__global__ __launch_bounds__(256) void agg2_kernel(const uint4* __restrict__ tbA,
                                                   const uint4* __restrict__ tbB,
                                                   const uint4* __restrict__ tbC,
                                                   const int* __restrict__ esrc,
                                                   const int* __restrict__ rs,
                                                   const float* __restrict__ bA,
                                                   const float* __restrict__ bB,
                                                   const float* __restrict__ bC,
                                                   float* __restrict__ out,
                                                   int ND, int NP, int o1, int o2) {
    __shared__ int sidx[4][64];
    const int w = threadIdx.x >> 6;
    const int lane = threadIdx.x & 63;
    const int wid = blockIdx.x * 4 + w;
    const int e8 = lane >> 3, c = lane & 7;
    if (wid >= ND + NP) return;
    float acc[8];
    auto zero = [&]() {
        for (int k = 0; k < 8; ++k) acc[k] = 0.f;
    };
    auto gather = [&](const uint4* __restrict__ tb, int e0, int e1) {
        for (int base = e0; base < e1; base += 64) {
            int cnt = min(64, e1 - base);
            if (lane < cnt) sidx[w][lane] = esrc[base + lane];
            int j = e8;
            for (; j + 8 < cnt; j += 16) {
                uint4 v0 = tb[(size_t)sidx[w][j] * 8 + c];
                uint4 v1 = tb[(size_t)sidx[w][j + 8] * 8 + c];
                acc[0] += bfl(v0.x) + bfl(v1.x);  acc[1] += bfh(v0.x) + bfh(v1.x);
                acc[2] += bfl(v0.y) + bfl(v1.y);  acc[3] += bfh(v0.y) + bfh(v1.y);
                acc[4] += bfl(v0.z) + bfl(v1.z);  acc[5] += bfh(v0.z) + bfh(v1.z);
                acc[6] += bfl(v0.w) + bfl(v1.w);  acc[7] += bfh(v0.w) + bfh(v1.w);
            }
            if (j < cnt) {
                uint4 v0 = tb[(size_t)sidx[w][j] * 8 + c];
                acc[0] += bfl(v0.x);  acc[1] += bfh(v0.x);
                acc[2] += bfl(v0.y);  acc[3] += bfh(v0.y);
                acc[4] += bfl(v0.z);  acc[5] += bfh(v0.z);
                acc[6] += bfl(v0.w);  acc[7] += bfh(v0.w);
            }
        }
        #pragma unroll
        for (int k = 0; k < 8; ++k) {
            acc[k] += __shfl_xor(acc[k], 8);
            acc[k] += __shfl_xor(acc[k], 16);
            acc[k] += __shfl_xor(acc[k], 32);
        }
    };
    if (wid < ND) {
        int e0 = rs[wid], e1 = rs[wid + 1];
        zero();
        gather(tbA, e0, e1);
        if (lane < 8) {
            float inv = 1.f / (float)max(e1 - e0, 1);
            float4 b0 = ((const float4*)bA)[c * 2];
            float4 b1 = ((const float4*)bA)[c * 2 + 1];
            float4 r0, r1;
            r0.x = acc[0] * inv + b0.x; r0.y = acc[1] * inv + b0.y;
            r0.z = acc[2] * inv + b0.z; r0.w = acc[3] * inv + b0.w;
            r1.x = acc[4] * inv + b1.x; r1.y = acc[5] * inv + b1.y;
            r1.z = acc[6] * inv + b1.z; r1.w = acc[7] * inv + b1.w;
            float4* op = (float4*)out + (size_t)wid * 16 + c * 2;
            op[0] = r0; op[1] = r1;
        }
    } else {
        int p = wid - ND;
        int g1 = o1 + p, g2 = o2 + p;
        int e0 = rs[g1], e1 = rs[g1 + 1];
        zero();
        gather(tbB, e0, e1);
        float res[8];
        float inv1 = 1.f / (float)max(e1 - e0, 1);
        #pragma unroll
        for (int k = 0; k < 8; ++k) res[k] = acc[k] * inv1;
        int f0 = rs[g2], f1 = rs[g2 + 1];
        zero();
        gather(tbC, f0, f1);
        if (lane < 8) {
            float inv2 = 1.f / (float)max(f1 - f0, 1);
            float4 bb0 = ((const float4*)bB)[c * 2];
            float4 bb1 = ((const float4*)bB)[c * 2 + 1];
            float4 bc0 = ((const float4*)bC)[c * 2];
            float4 bc1 = ((const float4*)bC)[c * 2 + 1];
            float4 r0, r1;
            r0.x = res[0] + acc[0] * inv2 + bb0.x + bc0.x;
            r0.y = res[1] + acc[1] * inv2 + bb0.y + bc0.y;
            r0.z = res[2] + acc[2] * inv2 + bb0.z + bc0.z;
            r0.w = res[3] + acc[3] * inv2 + bb0.w + bc0.w;
            r1.x = res[4] + acc[4] * inv2 + bb1.x + bc1.x;
            r1.y = res[5] + acc[5] * inv2 + bb1.y + bc1.y;
            r1.z = res[6] + acc[6] * inv2 + bb1.z + bc1.z;
            r1.w = res[7] + acc[7] * inv2 + bb1.w + bc1.w;
            float4* op = (float4*)out + (size_t)(ND + p) * 16 + c * 2;
            op[0] = r0; op[1] = r1;
        }
    }
}

// ---------------- launch ----------------

extern "C" void kernel_launch(void* const* d_in, const int* in_sizes, int n_in,
                              void* d_out, int out_size, void* d_ws, size_t ws_size,
                              hipStream_t stream) {
    const float* x_drug = (const float*)d_in[0];
    const float* x_prot = (const float*)d_in[1];
    const int* src[3] = { (const int*)d_in[2], (const int*)d_in[4], (const int*)d_in[6] };
    const int* dst[3] = { (const int*)d_in[3], (const int*)d_in[5], (const int*)d_in[7] };
    const float* W1[3] = { (const float*)d_in[8],  (const float*)d_in[10], (const float*)d_in[12] };
    const float* b1[3] = { (const float*)d_in[9],  (const float*)d_in[11], (const float*)d_in[13] };
    const float* W2[3] = { (const float*)d_in[14], (const float*)d_in[16], (const float*)d_in[18] };
    const float* b2[3] = { (const float*)d_in[15], (const float*)d_in[17], (const float*)d_in[19] };

    const int ND = in_sizes[0] / 128;
    const int NP = in_sizes[1] / 128;
    const int EC[3] = { in_sizes[2], in_sizes[4], in_sizes[6] };
    float* out = (float*)d_out;

    const int o1 = ND, o2 = ND + NP;
    const int TN = ND + 2 * NP;
    const int NBIN = (TN + (1 << BIN_SH) - 1) >> BIN_SH;
    const int e0c = EC[0], e01 = EC[0] + EC[1], e012 = EC[0] + EC[1] + EC[2];

    // workspace layout
    char* w = (char*)d_ws;
    ushort16* hd16 = (ushort16*)w; w += (size_t)ND * 128 * 2;
    ushort16* hp16 = (ushort16*)w; w += (size_t)NP * 128 * 2;
    ushort16* tbA  = (ushort16*)w; w += (size_t)ND * 128 * 2;
    ushort16* tbB  = (ushort16*)w; w += (size_t)ND * 128 * 2;
    ushort16* tbC  = (ushort16*)w; w += (size_t)NP * 128 * 2;
    ushort16* Wt[6];
    for (int r = 0; r < 3; ++r) { Wt[r] = (ushort16*)w; w += 128 * 128 * 2; }
    for (int r = 0; r < 3; ++r) { Wt[3 + r] = (ushort16*)w; w += 64 * 128 * 2; }
    int* ip = (int*)w;
    int* rs_all   = ip; ip += TN + 1;
    int* esrc_all = ip; ip += e012;
    int* ccur     = ip; ip += NBIN_MAX;
    // cpair aliases hd16+hp16: dead before agg1 writes them
    u64* cpair = (u64*)hd16;

    // ---- CSR build (part_a carries cvtW as tail) ----
    CvtWArgs cw;
    for (int r = 0; r < 3; ++r) { cw.W[r] = W1[r]; cw.W[3 + r] = W2[r]; }
    for (int r = 0; r < 6; ++r) cw.Wt[r] = Wt[r];
    init_ccur_kernel<<<1, 256, 0, stream>>>(ccur, NBIN);
    part_a_kernel<<<1024, 256, 0, stream>>>(src[0], dst[0], src[1], dst[1], src[2], dst[2],
                                            e0c, e01, e012, o1, o2, NBIN, ccur, cpair, cw);
    part_b_kernel<<<NBIN, 256, 0, stream>>>(cpair, ccur, NBIN, TN, e012, rs_all, esrc_all);

    auto gb64 = [](int n) { return (n + 63) / 64; };
    auto ab = [](int n) { return (n + 3) / 4; };

    // ---- layer 1 ----
    {
        Gemm3Args g;
        g.A[0] = x_drug; g.A[1] = x_drug; g.A[2] = x_prot;
        g.Wt[0] = Wt[0]; g.Wt[1] = Wt[1]; g.Wt[2] = Wt[2];
        g.Y[0] = tbA; g.Y[1] = tbB; g.Y[2] = tbC;
        g.N[0] = ND; g.N[1] = ND; g.N[2] = NP;
        g.nb0 = gb64(ND); g.nb01 = gb64(ND) * 2;
        int nblk = gb64(ND) * 2 + gb64(NP);
        gemm3_kernel<128, true><<<nblk, 256, 0, stream>>>(g);
    }
    agg1_kernel<<<ab(ND + NP), 256, 0, stream>>>((const uint4*)tbA, (const uint4*)tbB,
                                                 (const uint4*)tbC, esrc_all, rs_all,
                                                 b1[0], b1[1], b1[2],
                                                 (uint4*)hd16, (uint4*)hp16, ND, NP, o1, o2);

    // ---- layer 2 ----
    {
        Gemm3Args g;
        g.A[0] = hd16; g.A[1] = hd16; g.A[2] = hp16;
        g.Wt[0] = Wt[3]; g.Wt[1] = Wt[4]; g.Wt[2] = Wt[5];
        g.Y[0] = tbA; g.Y[1] = tbB; g.Y[2] = tbC;
        g.N[0] = ND; g.N[1] = ND; g.N[2] = NP;
        g.nb0 = gb64(ND); g.nb01 = gb64(ND) * 2;
        int nblk = gb64(ND) * 2 + gb64(NP);
        gemm3_kernel<64, false><<<nblk, 256, 0, stream>>>(g);
    }
    agg2_kernel<<<ab(ND + NP), 256, 0, stream>>>((const uint4*)tbA, (const uint4*)tbB,
                                                 (const uint4*)tbC, esrc_all, rs_all,
                                                 b2[0], b2[1], b2[2],
                                                 out, ND, NP, o1, o2);
}

// Round 19
// 229.753 us; speedup vs baseline: 1.6093x; 1.6093x over previous
//
#include <hip/hip_runtime.h>

typedef unsigned int uint32;
typedef unsigned short ushort16;
typedef unsigned long long u64;
using short8 = __attribute__((ext_vector_type(8))) short;
using f32x4  = __attribute__((ext_vector_type(4))) float;

__device__ __forceinline__ float bfl(uint32 v) { return __uint_as_float(v << 16); }
__device__ __forceinline__ float bfh(uint32 v) { return __uint_as_float(v & 0xffff0000u); }
__device__ __forceinline__ ushort16 f2bf(float f) {
    uint32 u = __float_as_uint(f);
    u += 0x7fffu + ((u >> 16) & 1u);   // RNE
    return (ushort16)(u >> 16);
}
__device__ __forceinline__ uint32 pack2(float x, float y) {
    return (uint32)f2bf(x) | ((uint32)f2bf(y) << 16);
}

// ---------------- CSR build: LDS-binned two-phase partition (round-17 proven form) ----------------
// LCAP 40 (51.8 KB LDS) -> 2-3 blocks/CU; grid 768; mid-loop flush spreads the
// counter atomics + write traffic over time (removing it serializes the final flush).

constexpr int BIN_SH   = 10;
constexpr int CAP_PAIR = 16384;
constexpr int LCAP     = 40;
constexpr int NBIN_MAX = 160;

struct CvtWArgs { const float* W[6]; ushort16* Wt[6]; };

__global__ void init_ccur_kernel(int* __restrict__ ccur, int nbin) {
    int b = threadIdx.x;
    if (b < nbin) ccur[b] = b * CAP_PAIR;
}

__global__ __launch_bounds__(256) void part_a_kernel(
        const int* __restrict__ s0, const int* __restrict__ d0,
        const int* __restrict__ s1, const int* __restrict__ d1,
        const int* __restrict__ s2, const int* __restrict__ d2,
        int e0, int e01, int e012, int o1, int o2, int nbin,
        int* __restrict__ ccur, u64* __restrict__ cpair, CvtWArgs a) {
    __shared__ u64 buf[NBIN_MAX][LCAP];
    __shared__ int lcnt[NBIN_MAX];
    const int tid = threadIdx.x;
    for (int b = tid; b < nbin; b += 256) lcnt[b] = 0;
    __syncthreads();
    const int step = gridDim.x * 1024;
    for (int base = blockIdx.x * 1024; base < e012; base += step) {
        #pragma unroll
        for (int k = 0; k < 4; ++k) {
            int i = base + tid + k * 256;
            if (i < e012) {
                int g, sv;
                if (i < e0)       { g = d0[i];            sv = s0[i]; }
                else if (i < e01) { g = o1 + d1[i - e0];  sv = s1[i - e0]; }
                else              { g = o2 + d2[i - e01]; sv = s2[i - e01]; }
                int bin = g >> BIN_SH;
                u64 pr = ((u64)(uint32)g << 32) | (uint32)sv;
                int slot = atomicAdd(&lcnt[bin], 1);
                if (slot < LCAP) {
                    buf[bin][slot] = pr;
                } else {                           // rare overflow: direct append
                    int p = atomicAdd(&ccur[bin], 1);
                    cpair[p] = pr;
                    atomicSub(&lcnt[bin], 1);
                }
            }
        }
        __syncthreads();
        if (tid < nbin) {                          // flush full 32-pair groups
            int cnt = min(lcnt[tid], LCAP);
            if (cnt >= 32) {
                int n = cnt & ~31;
                int p = atomicAdd(&ccur[tid], n);
                for (int k = 0; k < n; ++k) cpair[p + k] = buf[tid][k];
                for (int k = 0; k < cnt - n; ++k) buf[tid][k] = buf[tid][n + k];
                lcnt[tid] = cnt - n;
            }
        }
        __syncthreads();
    }
    if (tid < nbin) {                              // final partial flush
        int cnt = min(lcnt[tid], LCAP);
        if (cnt > 0) {
            int p = atomicAdd(&ccur[tid], cnt);
            for (int k = 0; k < cnt; ++k) cpair[p + k] = buf[tid][k];
        }
    }
    // ---- cvtW tail (independent; W[k][M] fp32 -> Wt[n][k] bf16) ----
    const int gid = blockIdx.x * 256 + tid;
    const int gstep = gridDim.x * 256;
    for (int i = gid; i < 3 * 16384 + 3 * 8192; i += gstep) {
        if (i < 3 * 16384) {
            int m = i / 16384, idx = i % 16384;
            int n = idx >> 7, k = idx & 127;
            a.Wt[m][n * 128 + k] = f2bf(a.W[m][k * 128 + n]);
        } else {
            int j = i - 3 * 16384;
            int m = 3 + j / 8192, idx = j % 8192;
            int n = idx >> 7, k = idx & 127;
            a.Wt[m][n * 128 + k] = f2bf(a.W[m][k * 64 + n]);
        }
    }
}

__global__ __launch_bounds__(64) void scan_bins_kernel(const int* __restrict__ ccur, int nbin,
                                                       int* __restrict__ cofs) {
    int lane = threadIdx.x;
    int run = 0;
    for (int base = 0; base < nbin; base += 64) {
        int b = base + lane;
        int c = (b < nbin) ? (ccur[b] - b * CAP_PAIR) : 0;
        int v = c;
        #pragma unroll
        for (int off = 1; off < 64; off <<= 1) {
            int u = __shfl_up(v, off);
            if (lane >= off) v += u;
        }
        if (b < nbin) cofs[b] = run + (v - c);
        run += __shfl(v, 63);
    }
    if (lane == 0) cofs[nbin] = run;
}

__global__ __launch_bounds__(256) void part_b_kernel(const u64* __restrict__ cpair,
                                                     const int* __restrict__ cofs,
                                                     int nbin, int tn, int e012,
                                                     int* __restrict__ rs,
                                                     int* __restrict__ esrc) {
    __shared__ int rs_l[1024];
    __shared__ int cur_l[1024];
    __shared__ int tsum[256];
    const int bin = blockIdx.x;
    const int t = threadIdx.x;
    const int g0 = bin << BIN_SH;
    const int gcnt = min(1024, tn - g0);
    const int pbase = bin * CAP_PAIR;
    const int obase = cofs[bin];
    const int cnt = cofs[bin + 1] - obase;
    #pragma unroll
    for (int k = 0; k < 4; ++k) cur_l[t + k * 256] = 0;
    __syncthreads();
    for (int i = t; i < cnt; i += 256) {
        int g = (int)(cpair[pbase + i] >> 32);
        atomicAdd(&cur_l[g - g0], 1);
    }
    __syncthreads();
    int v[4]; int s = 0;
    #pragma unroll
    for (int k = 0; k < 4; ++k) { v[k] = cur_l[t * 4 + k]; s += v[k]; }
    tsum[t] = s;
    __syncthreads();
    for (int off = 1; off < 256; off <<= 1) {
        int add = (t >= off) ? tsum[t - off] : 0;
        __syncthreads();
        tsum[t] += add;
        __syncthreads();
    }
    int run = (t ? tsum[t - 1] : 0);
    #pragma unroll
    for (int k = 0; k < 4; ++k) { rs_l[t * 4 + k] = run; run += v[k]; }
    __syncthreads();
    #pragma unroll
    for (int k = 0; k < 4; ++k) {
        int j = t + k * 256;
        if (j < gcnt) rs[g0 + j] = obase + rs_l[j];
    }
    if (bin == nbin - 1 && t == 0) rs[tn] = e012;
    #pragma unroll
    for (int k = 0; k < 4; ++k) cur_l[t + k * 256] = 0;
    __syncthreads();
    for (int i = t; i < cnt; i += 256) {
        u64 pr = cpair[pbase + i];
        int g = (int)(pr >> 32);
        int p = atomicAdd(&cur_l[g - g0], 1);
        esrc[obase + rs_l[g - g0] + p] = (int)(uint32)(pr & 0xffffffffu);
    }
}

// ---------------- fused triple GEMM, LDS-staged 64-row tiles (round-14 form) ----------------

struct Gemm3Args {
    const void* A[3];
    const ushort16* Wt[3];
    ushort16* Y[3];
    int N[3];
    int nb0, nb01;
};

template<int M, bool F32A>
__global__ __launch_bounds__(256) void gemm3_kernel(Gemm3Args g) {
    constexpr int NTW = M / 64;
    constexpr int CH  = M / 8;
    __shared__ short8 As[64 * 16];
    int b = blockIdx.x;
    int r = (b < g.nb0) ? 0 : ((b < g.nb01) ? 1 : 2);
    int bloc = b - ((r == 0) ? 0 : ((r == 1) ? g.nb0 : g.nb01));
    const int N = g.N[r];
    const int row0 = bloc * 64;
    const int tid = threadIdx.x;
    const int w = tid >> 6, l = tid & 63;
    const int lr = l & 15, lg = l >> 4;

    #pragma unroll
    for (int it = 0; it < 4; ++it) {
        int idx = it * 256 + tid;
        int row = idx >> 4, c = idx & 15;
        int grow = row0 + row;
        short8 v = {0, 0, 0, 0, 0, 0, 0, 0};
        if (grow < N) {
            if (F32A) {
                const float* gp = (const float*)g.A[r] + (size_t)grow * 128 + c * 8;
                float4 f0 = *(const float4*)gp;
                float4 f1 = *(const float4*)(gp + 4);
                v[0] = (short)f2bf(f0.x); v[1] = (short)f2bf(f0.y);
                v[2] = (short)f2bf(f0.z); v[3] = (short)f2bf(f0.w);
                v[4] = (short)f2bf(f1.x); v[5] = (short)f2bf(f1.y);
                v[6] = (short)f2bf(f1.z); v[7] = (short)f2bf(f1.w);
            } else {
                v = *(const short8*)((const ushort16*)g.A[r] + (size_t)grow * 128 + c * 8);
            }
        }
        As[row * 16 + (c ^ (row & 7))] = v;
    }
    __syncthreads();

    short8 bf[NTW][4];
    #pragma unroll
    for (int t = 0; t < NTW; ++t) {
        int n = w * (NTW * 16) + t * 16 + lr;
        const ushort16* wr = g.Wt[r] + (size_t)n * 128 + lg * 8;
        #pragma unroll
        for (int ks = 0; ks < 4; ++ks) bf[t][ks] = *(const short8*)(wr + ks * 32);
    }

    f32x4 acc[4][NTW];
    #pragma unroll
    for (int rt = 0; rt < 4; ++rt)
        #pragma unroll
        for (int t = 0; t < NTW; ++t) acc[rt][t] = (f32x4){0.f, 0.f, 0.f, 0.f};

    #pragma unroll
    for (int rt = 0; rt < 4; ++rt) {
        int row = rt * 16 + lr;
        short8 a[4];
        #pragma unroll
        for (int ks = 0; ks < 4; ++ks)
            a[ks] = As[row * 16 + ((lg + ks * 4) ^ (lr & 7))];
        #pragma unroll
        for (int t = 0; t < NTW; ++t)
            #pragma unroll
            for (int ks = 0; ks < 4; ++ks)
                acc[rt][t] = __builtin_amdgcn_mfma_f32_16x16x32_bf16(a[ks], bf[t][ks],
                                                                     acc[rt][t], 0, 0, 0);
    }

    __syncthreads();
    ushort16* Ys = (ushort16*)As;
    #pragma unroll
    for (int rt = 0; rt < 4; ++rt) {
        int row = rt * 16 + lg * 4;
        #pragma unroll
        for (int t = 0; t < NTW; ++t) {
            int col = w * (NTW * 16) + t * 16 + lr;
            int chx = (col >> 3);
            #pragma unroll
            for (int j = 0; j < 4; ++j) {
                int rr = row + j;
                Ys[rr * M + ((chx ^ (rr & 7)) << 3) + (col & 7)] = f2bf(acc[rt][t][j]);
            }
        }
    }
    __syncthreads();
    ushort16* Y = g.Y[r];
    #pragma unroll
    for (int it = 0; it < 64 * CH / 256; ++it) {
        int idx = it * 256 + tid;
        int row = idx / CH, c = idx % CH;
        int grow = row0 + row;
        if (grow < N) {
            short8 v = *(const short8*)&Ys[row * M + ((c ^ (row & 7)) << 3)];
            *(short8*)(Y + (size_t)grow * M + c * 8) = v;
        }
    }
}

// ---------------- fused aggregation (round-14 form: agg1 unroll-2) ----------------

__global__ __launch_bounds__(256) void agg1_kernel(const uint4* __restrict__ tbA,
                                                   const uint4* __restrict__ tbB,
                                                   const uint4* __restrict__ tbC,
                                                   const int* __restrict__ esrc,
                                                   const int* __restrict__ rs,
                                                   const float* __restrict__ bA,
                                                   const float* __restrict__ bB,
                                                   const float* __restrict__ bC,
                                                   uint4* __restrict__ hd,
                                                   uint4* __restrict__ hp,
                                                   int ND, int NP, int o1, int o2) {
    __shared__ int sidx[4][64];
    const int w = threadIdx.x >> 6;
    const int lane = threadIdx.x & 63;
    const int wid = blockIdx.x * 4 + w;
    const int q = lane >> 4, c = lane & 15;
    if (wid >= ND + NP) return;
    float acc[8];
    auto zero = [&]() {
        for (int k = 0; k < 8; ++k) acc[k] = 0.f;
    };
    auto gather = [&](const uint4* __restrict__ tb, int e0, int e1) {
        for (int base = e0; base < e1; base += 64) {
            int cnt = min(64, e1 - base);
            if (lane < cnt) sidx[w][lane] = esrc[base + lane];
            int j = q;
            for (; j + 4 < cnt; j += 8) {
                uint4 v0 = tb[(size_t)sidx[w][j] * 16 + c];
                uint4 v1 = tb[(size_t)sidx[w][j + 4] * 16 + c];
                acc[0] += bfl(v0.x) + bfl(v1.x);  acc[1] += bfh(v0.x) + bfh(v1.x);
                acc[2] += bfl(v0.y) + bfl(v1.y);  acc[3] += bfh(v0.y) + bfh(v1.y);
                acc[4] += bfl(v0.z) + bfl(v1.z);  acc[5] += bfh(v0.z) + bfh(v1.z);
                acc[6] += bfl(v0.w) + bfl(v1.w);  acc[7] += bfh(v0.w) + bfh(v1.w);
            }
            if (j < cnt) {
                uint4 v0 = tb[(size_t)sidx[w][j] * 16 + c];
                acc[0] += bfl(v0.x);  acc[1] += bfh(v0.x);
                acc[2] += bfl(v0.y);  acc[3] += bfh(v0.y);
                acc[4] += bfl(v0.z);  acc[5] += bfh(v0.z);
                acc[6] += bfl(v0.w);  acc[7] += bfh(v0.w);
            }
        }
        #pragma unroll
        for (int k = 0; k < 8; ++k) {
            acc[k] += __shfl_xor(acc[k], 16);
            acc[k] += __shfl_xor(acc[k], 32);
        }
    };
    if (wid < ND) {
        int e0 = rs[wid], e1 = rs[wid + 1];
        zero();
        gather(tbA, e0, e1);
        if (lane < 16) {
            float inv = 1.f / (float)max(e1 - e0, 1);
            float4 b0 = ((const float4*)bA)[c * 2];
            float4 b1 = ((const float4*)bA)[c * 2 + 1];
            hd[(size_t)wid * 16 + c] = make_uint4(
                pack2(acc[0] * inv + b0.x, acc[1] * inv + b0.y),
                pack2(acc[2] * inv + b0.z, acc[3] * inv + b0.w),
                pack2(acc[4] * inv + b1.x, acc[5] * inv + b1.y),
                pack2(acc[6] * inv + b1.z, acc[7] * inv + b1.w));
        }
    } else {
        int p = wid - ND;
        int g1 = o1 + p, g2 = o2 + p;
        int e0 = rs[g1], e1 = rs[g1 + 1];
        zero();
        gather(tbB, e0, e1);
        float res[8];
        float inv1 = 1.f / (float)max(e1 - e0, 1);
        #pragma unroll
        for (int k = 0; k < 8; ++k) res[k] = acc[k] * inv1;
        int f0 = rs[g2], f1 = rs[g2 + 1];
        zero();
        gather(tbC, f0, f1);
        if (lane < 16) {
            float inv2 = 1.f / (float)max(f1 - f0, 1);
            float4 bb0 = ((const float4*)bB)[c * 2];
            float4 bb1 = ((const float4*)bB)[c * 2 + 1];
            float4 bc0 = ((const float4*)bC)[c * 2];
            float4 bc1 = ((const float4*)bC)[c * 2 + 1];
            float r0 = res[0] + acc[0] * inv2 + bb0.x + bc0.x;
            float r1 = res[1] + acc[1] * inv2 + bb0.y + bc0.y;
            float r2 = res[2] + acc[2] * inv2 + bb0.z + bc0.z;
            float r3 = res[3] + acc[3] * inv2 + bb0.w + bc0.w;
            float r4 = res[4] + acc[4] * inv2 + bb1.x + bc1.x;
            float r5 = res[5] + acc[5] * inv2 + bb1.y + bc1.y;
            float r6 = res[6] + acc[6] * inv2 + bb1.z + bc1.z;
            float r7 = res[7] + acc[7] * inv2 + bb1.w + bc1.w;
            hp[(size_t)p * 16 + c] = make_uint4(pack2(r0, r1), pack2(r2, r3),
                                                pack2(r4, r5), pack2(r6, r7));
        }
    }
}

__global__ __launch_bounds__(256) void agg2_kernel(const uint4* __restrict__ tbA,
                                                   const uint4* __restrict__ tbB,
                                                   const uint4* __restrict__ tbC,
                                                   const int* __restrict__ esrc,
                                                   const int* __restrict__ rs,
                                                   const float* __restrict__ bA,
                                                   const float* __restrict__ bB,
                                                   const float* __restrict__ bC,
                                                   float* __restrict__ out,
                                                   int ND, int NP, int o1, int o2) {
    __shared__ int sidx[4][64];
    const int w = threadIdx.x >> 6;
    const int lane = threadIdx.x & 63;
    const int wid = blockIdx.x * 4 + w;
    const int e8 = lane >> 3, c = lane & 7;
    if (wid >= ND + NP) return;
    float acc[8];
    auto zero = [&]() {
        for (int k = 0; k < 8; ++k) acc[k] = 0.f;
    };
    auto gather = [&](const uint4* __restrict__ tb, int e0, int e1) {
        for (int base = e0; base < e1; base += 64) {
            int cnt = min(64, e1 - base);
            if (lane < cnt) sidx[w][lane] = esrc[base + lane];
            int j = e8;
            for (; j + 8 < cnt; j += 16) {
                uint4 v0 = tb[(size_t)sidx[w][j] * 8 + c];
                uint4 v1 = tb[(size_t)sidx[w][j + 8] * 8 + c];
                acc[0] += bfl(v0.x) + bfl(v1.x);  acc[1] += bfh(v0.x) + bfh(v1.x);
                acc[2] += bfl(v0.y) + bfl(v1.y);  acc[3] += bfh(v0.y) + bfh(v1.y);
                acc[4] += bfl(v0.z) + bfl(v1.z);  acc[5] += bfh(v0.z) + bfh(v1.z);
                acc[6] += bfl(v0.w) + bfl(v1.w);  acc[7] += bfh(v0.w) + bfh(v1.w);
            }
            if (j < cnt) {
                uint4 v0 = tb[(size_t)sidx[w][j] * 8 + c];
                acc[0] += bfl(v0.x);  acc[1] += bfh(v0.x);
                acc[2] += bfl(v0.y);  acc[3] += bfh(v0.y);
                acc[4] += bfl(v0.z);  acc[5] += bfh(v0.z);
                acc[6] += bfl(v0.w);  acc[7] += bfh(v0.w);
            }
        }
        #pragma unroll
        for (int k = 0; k < 8; ++k) {
            acc[k] += __shfl_xor(acc[k], 8);
            acc[k] += __shfl_xor(acc[k], 16);
            acc[k] += __shfl_xor(acc[k], 32);
        }
    };
    if (wid < ND) {
        int e0 = rs[wid], e1 = rs[wid + 1];
        zero();
        gather(tbA, e0, e1);
        if (lane < 8) {
            float inv = 1.f / (float)max(e1 - e0, 1);
            float4 b0 = ((const float4*)bA)[c * 2];
            float4 b1 = ((const float4*)bA)[c * 2 + 1];
            float4 r0, r1;
            r0.x = acc[0] * inv + b0.x; r0.y = acc[1] * inv + b0.y;
            r0.z = acc[2] * inv + b0.z; r0.w = acc[3] * inv + b0.w;
            r1.x = acc[4] * inv + b1.x; r1.y = acc[5] * inv + b1.y;
            r1.z = acc[6] * inv + b1.z; r1.w = acc[7] * inv + b1.w;
            float4* op = (float4*)out + (size_t)wid * 16 + c * 2;
            op[0] = r0; op[1] = r1;
        }
    } else {
        int p = wid - ND;
        int g1 = o1 + p, g2 = o2 + p;
        int e0 = rs[g1], e1 = rs[g1 + 1];
        zero();
        gather(tbB, e0, e1);
        float res[8];
        float inv1 = 1.f / (float)max(e1 - e0, 1);
        #pragma unroll
        for (int k = 0; k < 8; ++k) res[k] = acc[k] * inv1;
        int f0 = rs[g2], f1 = rs[g2 + 1];
        zero();
        gather(tbC, f0, f1);
        if (lane < 8) {
            float inv2 = 1.f / (float)max(f1 - f0, 1);
            float4 bb0 = ((const float4*)bB)[c * 2];
            float4 bb1 = ((const float4*)bB)[c * 2 + 1];
            float4 bc0 = ((const float4*)bC)[c * 2];
            float4 bc1 = ((const float4*)bC)[c * 2 + 1];
            float4 r0, r1;
            r0.x = res[0] + acc[0] * inv2 + bb0.x + bc0.x;
            r0.y = res[1] + acc[1] * inv2 + bb0.y + bc0.y;
            r0.z = res[2] + acc[2] * inv2 + bb0.z + bc0.z;
            r0.w = res[3] + acc[3] * inv2 + bb0.w + bc0.w;
            r1.x = res[4] + acc[4] * inv2 + bb1.x + bc1.x;
            r1.y = res[5] + acc[5] * inv2 + bb1.y + bc1.y;
            r1.z = res[6] + acc[6] * inv2 + bb1.z + bc1.z;
            r1.w = res[7] + acc[7] * inv2 + bb1.w + bc1.w;
            float4* op = (float4*)out + (size_t)(ND + p) * 16 + c * 2;
            op[0] = r0; op[1] = r1;
        }
    }
}

// ---------------- launch ----------------

extern "C" void kernel_launch(void* const* d_in, const int* in_sizes, int n_in,
                              void* d_out, int out_size, void* d_ws, size_t ws_size,
                              hipStream_t stream) {
    const float* x_drug = (const float*)d_in[0];
    const float* x_prot = (const float*)d_in[1];
    const int* src[3] = { (const int*)d_in[2], (const int*)d_in[4], (const int*)d_in[6] };
    const int* dst[3] = { (const int*)d_in[3], (const int*)d_in[5], (const int*)d_in[7] };
    const float* W1[3] = { (const float*)d_in[8],  (const float*)d_in[10], (const float*)d_in[12] };
    const float* b1[3] = { (const float*)d_in[9],  (const float*)d_in[11], (const float*)d_in[13] };
    const float* W2[3] = { (const float*)d_in[14], (const float*)d_in[16], (const float*)d_in[18] };
    const float* b2[3] = { (const float*)d_in[15], (const float*)d_in[17], (const float*)d_in[19] };

    const int ND = in_sizes[0] / 128;
    const int NP = in_sizes[1] / 128;
    const int EC[3] = { in_sizes[2], in_sizes[4], in_sizes[6] };
    float* out = (float*)d_out;

    const int o1 = ND, o2 = ND + NP;
    const int TN = ND + 2 * NP;
    const int NBIN = (TN + (1 << BIN_SH) - 1) >> BIN_SH;
    const int e0c = EC[0], e01 = EC[0] + EC[1], e012 = EC[0] + EC[1] + EC[2];

    // workspace layout
    char* w = (char*)d_ws;
    ushort16* hd16 = (ushort16*)w; w += (size_t)ND * 128 * 2;
    ushort16* hp16 = (ushort16*)w; w += (size_t)NP * 128 * 2;
    ushort16* tbA  = (ushort16*)w; w += (size_t)ND * 128 * 2;
    ushort16* tbB  = (ushort16*)w; w += (size_t)ND * 128 * 2;
    ushort16* tbC  = (ushort16*)w; w += (size_t)NP * 128 * 2;
    ushort16* Wt[6];
    for (int r = 0; r < 3; ++r) { Wt[r] = (ushort16*)w; w += 128 * 128 * 2; }
    for (int r = 0; r < 3; ++r) { Wt[3 + r] = (ushort16*)w; w += 64 * 128 * 2; }
    int* ip = (int*)w;
    int* rs_all   = ip; ip += TN + 1;
    int* esrc_all = ip; ip += e012;
    int* ccur     = ip; ip += NBIN_MAX;
    int* cofs     = ip; ip += NBIN_MAX + 1;
    // cpair aliases hd16+hp16: dead before agg1 writes them
    u64* cpair = (u64*)hd16;

    // ---- CSR build (part_a carries cvtW as tail) ----
    CvtWArgs cw;
    for (int r = 0; r < 3; ++r) { cw.W[r] = W1[r]; cw.W[3 + r] = W2[r]; }
    for (int r = 0; r < 6; ++r) cw.Wt[r] = Wt[r];
    init_ccur_kernel<<<1, 256, 0, stream>>>(ccur, NBIN);
    part_a_kernel<<<768, 256, 0, stream>>>(src[0], dst[0], src[1], dst[1], src[2], dst[2],
                                           e0c, e01, e012, o1, o2, NBIN, ccur, cpair, cw);
    scan_bins_kernel<<<1, 64, 0, stream>>>(ccur, NBIN, cofs);
    part_b_kernel<<<NBIN, 256, 0, stream>>>(cpair, cofs, NBIN, TN, e012, rs_all, esrc_all);

    auto gb64 = [](int n) { return (n + 63) / 64; };
    auto ab = [](int n) { return (n + 3) / 4; };

    // ---- layer 1 ----
    {
        Gemm3Args g;
        g.A[0] = x_drug; g.A[1] = x_drug; g.A[2] = x_prot;
        g.Wt[0] = Wt[0]; g.Wt[1] = Wt[1]; g.Wt[2] = Wt[2];
        g.Y[0] = tbA; g.Y[1] = tbB; g.Y[2] = tbC;
        g.N[0] = ND; g.N[1] = ND; g.N[2] = NP;
        g.nb0 = gb64(ND); g.nb01 = gb64(ND) * 2;
        int nblk = gb64(ND) * 2 + gb64(NP);
        gemm3_kernel<128, true><<<nblk, 256, 0, stream>>>(g);
    }
    agg1_kernel<<<ab(ND + NP), 256, 0, stream>>>((const uint4*)tbA, (const uint4*)tbB,
                                                 (const uint4*)tbC, esrc_all, rs_all,
                                                 b1[0], b1[1], b1[2],
                                                 (uint4*)hd16, (uint4*)hp16, ND, NP, o1, o2);

    // ---- layer 2 ----
    {
        Gemm3Args g;
        g.A[0] = hd16; g.A[1] = hd16; g.A[2] = hp16;
        g.Wt[0] = Wt[3]; g.Wt[1] = Wt[4]; g.Wt[2] = Wt[5];
        g.Y[0] = tbA; g.Y[1] = tbB; g.Y[2] = tbC;
        g.N[0] = ND; g.N[1] = ND; g.N[2] = NP;
        g.nb0 = gb64(ND); g.nb01 = gb64(ND) * 2;
        int nblk = gb64(ND) * 2 + gb64(NP);
        gemm3_kernel<64, false><<<nblk, 256, 0, stream>>>(g);
    }
    agg2_kernel<<<ab(ND + NP), 256, 0, stream>>>((const uint4*)tbA, (const uint4*)tbB,
                                                 (const uint4*)tbC, esrc_all, rs_all,
                                                 b2[0], b2[1], b2[2],
                                                 out, ND, NP, o1, o2);
}